// Round 1
// baseline (1305.474 us; speedup 1.0000x reference)
//
#include <hip/hip_runtime.h>

#define N_SERVICES 50000
#define N_EDGES    1600000
#define EMB        32
#define BATCH      2048
#define FIN        128   // (CONTEXT+1)*EMB

typedef __attribute__((ext_vector_type(4))) float f4;

// ---------------- degree / normalization ----------------

__global__ void k_init_deg(float* __restrict__ deg) {
    int i = blockIdx.x * 256 + threadIdx.x;
    if (i < N_SERVICES) deg[i] = 1.0f;   // self-loop
}

__global__ void k_count_deg(const int* __restrict__ dst, float* __restrict__ deg) {
    int e = blockIdx.x * 256 + threadIdx.x;
    if (e < N_EDGES) atomicAdd(&deg[dst[e]], 1.0f);
}

__global__ void k_finish_dis(float* __restrict__ deg) {
    int i = blockIdx.x * 256 + threadIdx.x;
    if (i < N_SERVICES) deg[i] = rsqrtf(deg[i]);  // deg >= 1 always
}

// ---------------- GCN layer pieces ----------------

// h = in @ W   (in: [N,32], W: [32,32])
__global__ void k_transform(const float* __restrict__ in, const float* __restrict__ W,
                            float* __restrict__ h) {
    __shared__ float Ws[EMB][EMB + 1];
    __shared__ float rows[8][EMB];
    int t = threadIdx.x;
    int j = t & 31, li = t >> 5;
    for (int i = t; i < EMB * EMB; i += 256) Ws[i >> 5][i & 31] = W[i];
    int node = blockIdx.x * 8 + li;
    if (node < N_SERVICES) rows[li][j] = in[node * EMB + j];
    __syncthreads();
    if (node < N_SERVICES) {
        float acc = 0.f;
#pragma unroll
        for (int k = 0; k < EMB; ++k) acc = fmaf(rows[li][k], Ws[k][j], acc);
        h[node * EMB + j] = acc;
    }
}

// out[i][:] = h[i][:] * dis[i]^2   (self-loop message)
__global__ void k_self_init(const float* __restrict__ h, const float* __restrict__ dis,
                            float* __restrict__ out) {
    int t = blockIdx.x * 256 + threadIdx.x;
    if (t < N_SERVICES * EMB) {
        float di = dis[t >> 5];
        out[t] = h[t] * di * di;
    }
}

// out[dst][j] += h[src][j] * dis[src]*dis[dst]
__global__ void k_edge_scatter(const int* __restrict__ src, const int* __restrict__ dst,
                               const float* __restrict__ dis, const float* __restrict__ h,
                               float* __restrict__ out) {
    unsigned long long t = (unsigned long long)blockIdx.x * 256 + threadIdx.x;
    // grid sized exactly: N_EDGES*32 threads
    int e = (int)(t >> 5), j = (int)(t & 31);
    int s = src[e], d = dst[e];
    float norm = dis[s] * dis[d];
    atomicAdd(&out[d * EMB + j], h[s * EMB + j] * norm);
}

template <bool RELU>
__global__ void k_bias(float* __restrict__ g, const float* __restrict__ b) {
    int t = blockIdx.x * 256 + threadIdx.x;
    if (t < N_SERVICES * EMB) {
        float v = g[t] + b[t & 31];
        g[t] = RELU ? fmaxf(v, 0.f) : v;
    }
}

// ---------------- feature gather ----------------

__global__ void k_gather(const int* __restrict__ user_idx, const int* __restrict__ ctx_idx,
                         const float* __restrict__ user_emb, const float* __restrict__ g2,
                         float* __restrict__ x) {
    int t = blockIdx.x * 256 + threadIdx.x;  // grid exact: BATCH*FIN
    int b = t >> 7, p = t & 127;
    float v;
    if (p < EMB) {
        v = user_emb[user_idx[b] * EMB + p];
    } else {
        int c = (p - EMB) >> 5, j = p & 31;
        v = g2[ctx_idx[b * 3 + c] * EMB + j];
    }
    x[t] = v;
}

// ---------------- final GEMM: [2048,128] @ [128,50000] + bias ----------------
// BM=64, BN=64, full K=128 staged in LDS, 256 threads, 4x4 micro-tile/thread.

__global__ __launch_bounds__(256) void k_gemm(
    const float* __restrict__ x, const float* __restrict__ W,
    const float* __restrict__ bias, float* __restrict__ out) {
    __shared__ float xs[64][132];   // +4 pad: keeps f4 alignment, breaks bank conflict
    __shared__ float ws[128][64];
    int t = threadIdx.x;
    int n0 = blockIdx.x * 64;
    int m0 = blockIdx.y * 64;

#pragma unroll 4
    for (int i = 0; i < 32; ++i) {
        int flat = i * 256 + t;
        int m = flat >> 7, k = flat & 127;
        xs[m][k] = x[(m0 + m) * FIN + k];
    }
#pragma unroll 4
    for (int i = 0; i < 32; ++i) {
        int flat = i * 256 + t;
        int k = flat >> 6, n = flat & 63;
        int gn = n0 + n;
        ws[k][n] = (gn < N_SERVICES) ? W[k * N_SERVICES + gn] : 0.f;
    }
    __syncthreads();

    int tn = t & 15, tm = t >> 4;
    f4 acc[4] = {};   // acc[r] = 4 output columns for row r
#pragma unroll 8
    for (int k = 0; k < FIN; k += 4) {
        f4 a[4], b[4];
#pragma unroll
        for (int r = 0; r < 4; ++r) a[r] = *(const f4*)&xs[tm * 4 + r][k];
#pragma unroll
        for (int kk = 0; kk < 4; ++kk) b[kk] = *(const f4*)&ws[k + kk][tn * 4];
#pragma unroll
        for (int kk = 0; kk < 4; ++kk)
#pragma unroll
            for (int r = 0; r < 4; ++r)
                acc[r] += a[r][kk] * b[kk];
    }

    int gn = n0 + tn * 4;
    if (gn < N_SERVICES) {
        f4 bv = *(const f4*)&bias[gn];
#pragma unroll
        for (int r = 0; r < 4; ++r) {
            f4 v = acc[r] + bv;
            int m = m0 + tm * 4 + r;
            *(f4*)&out[(size_t)m * N_SERVICES + gn] = v;
        }
    }
}

// ---------------- launch ----------------

extern "C" void kernel_launch(void* const* d_in, const int* in_sizes, int n_in,
                              void* d_out, int out_size, void* d_ws, size_t ws_size,
                              hipStream_t stream) {
    const int*   user_idx    = (const int*)d_in[0];
    const int*   ctx_idx     = (const int*)d_in[1];
    const int*   ei          = (const int*)d_in[2];
    const float* user_emb    = (const float*)d_in[3];
    const float* service_emb = (const float*)d_in[4];
    const float* W1          = (const float*)d_in[5];
    const float* b1          = (const float*)d_in[6];
    const float* W2          = (const float*)d_in[7];
    const float* b2          = (const float*)d_in[8];
    const float* fcW         = (const float*)d_in[9];
    const float* fcb         = (const float*)d_in[10];
    float* out = (float*)d_out;

    const int* src = ei;
    const int* dst = ei + N_EDGES;

    char* ws = (char*)d_ws;
    float* dis = (float*)(ws);                         //  50000 f
    float* h   = (float*)(ws + 200000);                // 1.6M f
    float* g1  = (float*)(ws + 200000 + 6400000);      // 1.6M f
    float* g2  = (float*)(ws + 200000 + 12800000);     // 1.6M f
    float* xb  = (float*)(ws + 200000 + 19200000);     // 262144 f  (total ~20.4MB)

    k_init_deg  <<<196,    256, 0, stream>>>(dis);
    k_count_deg <<<6250,   256, 0, stream>>>(dst, dis);
    k_finish_dis<<<196,    256, 0, stream>>>(dis);

    // layer 1 (+ReLU)
    k_transform   <<<6250,   256, 0, stream>>>(service_emb, W1, h);
    k_self_init   <<<6250,   256, 0, stream>>>(h, dis, g1);
    k_edge_scatter<<<200000, 256, 0, stream>>>(src, dst, dis, h, g1);
    k_bias<true>  <<<6250,   256, 0, stream>>>(g1, b1);

    // layer 2
    k_transform   <<<6250,   256, 0, stream>>>(g1, W2, h);
    k_self_init   <<<6250,   256, 0, stream>>>(h, dis, g2);
    k_edge_scatter<<<200000, 256, 0, stream>>>(src, dst, dis, h, g2);
    k_bias<false> <<<6250,   256, 0, stream>>>(g2, b2);

    k_gather<<<1024, 256, 0, stream>>>(user_idx, ctx_idx, user_emb, g2, xb);

    dim3 grid((N_SERVICES + 63) / 64, BATCH / 64);
    k_gemm<<<grid, 256, 0, stream>>>(xb, fcW, fcb, out);
}

// Round 2
// 729.270 us; speedup vs baseline: 1.7901x; 1.7901x over previous
//
#include <hip/hip_runtime.h>

#define N_SERVICES 50000
#define N_PAD      50048   // 782*64, padded for GEMM tiles
#define N_EDGES    1600000
#define EMB        32
#define BATCH      2048
#define FIN        128     // (CONTEXT+1)*EMB

typedef __attribute__((ext_vector_type(4))) float f32x4;
typedef __attribute__((ext_vector_type(8))) short short8;

__device__ inline short f2bf(float f) {
    unsigned u = __float_as_uint(f);
    unsigned r = (u + 0x7FFFu + ((u >> 16) & 1u)) >> 16;
    return (short)r;
}

// ---------------- degree / normalization ----------------

__global__ void k_init_deg(float* __restrict__ deg) {
    int i = blockIdx.x * 256 + threadIdx.x;
    if (i < N_SERVICES) deg[i] = 1.0f;   // self-loop
}

__global__ void k_count_deg(const int* __restrict__ dst, float* __restrict__ deg) {
    int e = blockIdx.x * 256 + threadIdx.x;
    if (e < N_EDGES) atomicAdd(&deg[dst[e]], 1.0f);
}

__global__ void k_finish_dis(float* __restrict__ deg) {
    int i = blockIdx.x * 256 + threadIdx.x;
    if (i < N_SERVICES) deg[i] = rsqrtf(deg[i]);  // deg >= 1 always
}

// ---------------- GCN layer pieces ----------------

__global__ void k_transform(const float* __restrict__ in, const float* __restrict__ W,
                            float* __restrict__ h) {
    __shared__ float Ws[EMB][EMB + 1];
    __shared__ float rows[8][EMB];
    int t = threadIdx.x;
    int j = t & 31, li = t >> 5;
    for (int i = t; i < EMB * EMB; i += 256) Ws[i >> 5][i & 31] = W[i];
    int node = blockIdx.x * 8 + li;
    if (node < N_SERVICES) rows[li][j] = in[node * EMB + j];
    __syncthreads();
    if (node < N_SERVICES) {
        float acc = 0.f;
#pragma unroll
        for (int k = 0; k < EMB; ++k) acc = fmaf(rows[li][k], Ws[k][j], acc);
        h[node * EMB + j] = acc;
    }
}

__global__ void k_self_init(const float* __restrict__ h, const float* __restrict__ dis,
                            float* __restrict__ out) {
    int t = blockIdx.x * 256 + threadIdx.x;
    if (t < N_SERVICES * EMB) {
        float di = dis[t >> 5];
        out[t] = h[t] * di * di;
    }
}

__global__ void k_edge_scatter(const int* __restrict__ src, const int* __restrict__ dst,
                               const float* __restrict__ dis, const float* __restrict__ h,
                               float* __restrict__ out) {
    unsigned long long t = (unsigned long long)blockIdx.x * 256 + threadIdx.x;
    int e = (int)(t >> 5), j = (int)(t & 31);
    int s = src[e], d = dst[e];
    float norm = dis[s] * dis[d];
    atomicAdd(&out[d * EMB + j], h[s * EMB + j] * norm);
}

template <bool RELU>
__global__ void k_bias(float* __restrict__ g, const float* __restrict__ b) {
    int t = blockIdx.x * 256 + threadIdx.x;
    if (t < N_SERVICES * EMB) {
        float v = g[t] + b[t & 31];
        g[t] = RELU ? fmaxf(v, 0.f) : v;
    }
}

// ---------------- feature gather (emit bf16) ----------------

__global__ void k_gather(const int* __restrict__ user_idx, const int* __restrict__ ctx_idx,
                         const float* __restrict__ user_emb, const float* __restrict__ g2,
                         short* __restrict__ x) {
    int t = blockIdx.x * 256 + threadIdx.x;  // grid exact: BATCH*FIN
    int b = t >> 7, p = t & 127;
    float v;
    if (p < EMB) {
        v = user_emb[user_idx[b] * EMB + p];
    } else {
        int c = (p - EMB) >> 5, j = p & 31;
        v = g2[ctx_idx[b * 3 + c] * EMB + j];
    }
    x[t] = f2bf(v);
}

// ---------------- fc_W transpose+convert: [128][50000] f32 -> [50048][128] bf16 ----

__global__ __launch_bounds__(256) void k_cvtW(const float* __restrict__ W,
                                              short* __restrict__ Wt) {
    __shared__ short lds[128][33];
    int t = threadIdx.x;
    int n0 = blockIdx.x * 32;
    int nx = t & 31;
    int n  = n0 + nx;
    int kg = t >> 5;                 // 0..7
#pragma unroll
    for (int r = 0; r < 16; ++r) {
        int k = r * 8 + kg;
        float v = (n < N_SERVICES) ? W[k * N_SERVICES + n] : 0.f;
        lds[k][nx] = f2bf(v);
    }
    __syncthreads();
    int nr = t >> 3;                 // 0..31 (row within tile)
    int kc = (t & 7) * 16;           // k-chunk
    short tmp[16];
#pragma unroll
    for (int i = 0; i < 16; ++i) tmp[i] = lds[kc + i][nr];
    short8* dstp = (short8*)(Wt + (size_t)(n0 + nr) * FIN + kc);
    dstp[0] = *(short8*)&tmp[0];
    dstp[1] = *(short8*)&tmp[8];
}

// ---------------- final GEMM via bf16 MFMA ----------------
// A: [2048][128] bf16 row-major.  Bt: [50048][128] bf16 (fc_W transposed).
// Block: 256 thr = 4 waves; wave w computes rows m0+w*16..+16, cols n0..n0+64.

__global__ __launch_bounds__(256) void k_gemm_mfma(
    const short* __restrict__ A, const short* __restrict__ Bt,
    const float* __restrict__ bias, float* __restrict__ out) {
    int t = threadIdx.x;
    int w = t >> 6;
    int l = t & 63;
    int lr = l & 15;                 // A row / B col within fragment
    int lg = l >> 4;                 // k-group (8 consecutive k each)
    int n0 = blockIdx.x * 64;
    int m0 = blockIdx.y * 64 + w * 16;

    short8 a[4];
#pragma unroll
    for (int ks = 0; ks < 4; ++ks)
        a[ks] = *(const short8*)(A + (size_t)(m0 + lr) * FIN + ks * 32 + lg * 8);

    f32x4 acc[4] = {};
#pragma unroll
    for (int f = 0; f < 4; ++f) {
        int col = n0 + f * 16 + lr;
        const short* brow = Bt + (size_t)col * FIN + lg * 8;
#pragma unroll
        for (int ks = 0; ks < 4; ++ks) {
            short8 b = *(const short8*)(brow + ks * 32);
            acc[f] = __builtin_amdgcn_mfma_f32_16x16x32_bf16(a[ks], b, acc[f], 0, 0, 0);
        }
    }

    int row = m0 + lg * 4;
#pragma unroll
    for (int f = 0; f < 4; ++f) {
        int col = n0 + f * 16 + lr;
        if (col < N_SERVICES) {
            float bv = bias[col];
#pragma unroll
            for (int r = 0; r < 4; ++r)
                out[(size_t)(row + r) * N_SERVICES + col] = acc[f][r] + bv;
        }
    }
}

// ---------------- launch ----------------

extern "C" void kernel_launch(void* const* d_in, const int* in_sizes, int n_in,
                              void* d_out, int out_size, void* d_ws, size_t ws_size,
                              hipStream_t stream) {
    const int*   user_idx    = (const int*)d_in[0];
    const int*   ctx_idx     = (const int*)d_in[1];
    const int*   ei          = (const int*)d_in[2];
    const float* user_emb    = (const float*)d_in[3];
    const float* service_emb = (const float*)d_in[4];
    const float* W1          = (const float*)d_in[5];
    const float* b1          = (const float*)d_in[6];
    const float* W2          = (const float*)d_in[7];
    const float* b2          = (const float*)d_in[8];
    const float* fcW         = (const float*)d_in[9];
    const float* fcb         = (const float*)d_in[10];
    float* out = (float*)d_out;

    const int* src = ei;
    const int* dst = ei + N_EDGES;

    char* ws = (char*)d_ws;
    float* dis = (float*)(ws);                  // 200,000 B
    float* h   = (float*)(ws + 200000);         // 6,400,000 B (transform out, both layers)
    float* g1  = (float*)(ws + 6600000);        // 6,400,000 B (layer1 out, then layer2 out)
    short* xb  = (short*)(ws + 13000000);       //   524,288 B (bf16 features)
    short* Wt  = (short*)(ws + 13524288);       // 12,812,288 B (bf16 fc_W^T, padded)
    // total ~26.3 MB

    // fc_W convert/transpose (independent — run first)
    k_cvtW<<<N_PAD / 32, 256, 0, stream>>>(fcW, Wt);

    k_init_deg  <<<196,  256, 0, stream>>>(dis);
    k_count_deg <<<6250, 256, 0, stream>>>(dst, dis);
    k_finish_dis<<<196,  256, 0, stream>>>(dis);

    // layer 1 (+ReLU)
    k_transform   <<<6250,   256, 0, stream>>>(service_emb, W1, h);
    k_self_init   <<<6250,   256, 0, stream>>>(h, dis, g1);
    k_edge_scatter<<<200000, 256, 0, stream>>>(src, dst, dis, h, g1);
    k_bias<true>  <<<6250,   256, 0, stream>>>(g1, b1);

    // layer 2 (reuse h and g1)
    k_transform   <<<6250,   256, 0, stream>>>(g1, W2, h);
    k_self_init   <<<6250,   256, 0, stream>>>(h, dis, g1);
    k_edge_scatter<<<200000, 256, 0, stream>>>(src, dst, dis, h, g1);
    k_bias<false> <<<6250,   256, 0, stream>>>(g1, b2);

    k_gather<<<BATCH * FIN / 256, 256, 0, stream>>>(user_idx, ctx_idx, user_emb, g1, xb);

    dim3 grid(N_PAD / 64, BATCH / 64);
    k_gemm_mfma<<<grid, 256, 0, stream>>>(xb, Wt, fcb, out);
}

// Round 3
// 556.200 us; speedup vs baseline: 2.3471x; 1.3112x over previous
//
#include <hip/hip_runtime.h>

#define N_SERVICES 50000
#define N_PAD      50048   // 782*64
#define N_EDGES    1600000
#define EMB        32
#define BATCH      2048
#define FIN        128     // (CONTEXT+1)*EMB

typedef __attribute__((ext_vector_type(4))) float f32x4;
typedef __attribute__((ext_vector_type(8))) short short8;

__device__ inline short f2bf(float f) {
    unsigned u = __float_as_uint(f);
    unsigned r = (u + 0x7FFFu + ((u >> 16) & 1u)) >> 16;
    return (short)r;
}

// ---------------- degree / dis ----------------

__global__ void k_count_degi(const int* __restrict__ dst, int* __restrict__ degi) {
    int e = blockIdx.x * 256 + threadIdx.x;
    if (e < N_EDGES) atomicAdd(&degi[dst[e]], 1);
}

__global__ void k_dis(const int* __restrict__ degi, float* __restrict__ dis) {
    int i = blockIdx.x * 256 + threadIdx.x;
    if (i < N_SERVICES) dis[i] = rsqrtf((float)(degi[i] + 1));  // +1 self-loop
}

// ---------------- prefix scan (3 kernels) ----------------

__global__ void k_scan_block(const int* __restrict__ degi, int* __restrict__ tmp,
                             int* __restrict__ blocksum) {
    __shared__ int s[256];
    int t = threadIdx.x, i = blockIdx.x * 256 + t;
    int v = (i < N_SERVICES) ? degi[i] : 0;
    s[t] = v;
    __syncthreads();
#pragma unroll
    for (int o = 1; o < 256; o <<= 1) {
        int x = 0;
        if (t >= o) x = s[t - o];
        __syncthreads();
        if (t >= o) s[t] += x;
        __syncthreads();
    }
    if (i < N_SERVICES) tmp[i] = s[t] - v;       // exclusive
    if (t == 255) blocksum[blockIdx.x] = s[255];
}

__global__ void k_scan_part(int* __restrict__ blocksum) {
    __shared__ int s[256];
    int t = threadIdx.x;
    int v = (t < 196) ? blocksum[t] : 0;
    s[t] = v;
    __syncthreads();
#pragma unroll
    for (int o = 1; o < 256; o <<= 1) {
        int x = 0;
        if (t >= o) x = s[t - o];
        __syncthreads();
        if (t >= o) s[t] += x;
        __syncthreads();
    }
    if (t < 196) blocksum[t] = s[t] - v;         // exclusive in place
}

__global__ void k_scan_fin(const int* __restrict__ tmp, const int* __restrict__ blocksum,
                           int* __restrict__ row_start, int* __restrict__ cursor) {
    int i = blockIdx.x * 256 + threadIdx.x;
    if (i < N_SERVICES) {
        int v = tmp[i] + blocksum[blockIdx.x];
        row_start[i] = v;
        cursor[i] = v;
    }
    if (i == 0) row_start[N_SERVICES] = N_EDGES;
}

__global__ void k_fill(const int* __restrict__ src, const int* __restrict__ dst,
                       int* __restrict__ cursor, int* __restrict__ csr_src) {
    int e = blockIdx.x * 256 + threadIdx.x;
    if (e < N_EDGES) {
        int pos = atomicAdd(&cursor[dst[e]], 1);
        csr_src[pos] = src[e];
    }
}

// ---------------- GCN pieces ----------------

__global__ void k_transform(const float* __restrict__ in, const float* __restrict__ W,
                            float* __restrict__ h) {
    __shared__ float Ws[EMB][EMB + 1];
    __shared__ float rows[8][EMB];
    int t = threadIdx.x;
    int j = t & 31, li = t >> 5;
    for (int i = t; i < EMB * EMB; i += 256) Ws[i >> 5][i & 31] = W[i];
    int node = blockIdx.x * 8 + li;
    if (node < N_SERVICES) rows[li][j] = in[node * EMB + j];
    __syncthreads();
    if (node < N_SERVICES) {
        float acc = 0.f;
#pragma unroll
        for (int k = 0; k < EMB; ++k) acc = fmaf(rows[li][k], Ws[k][j], acc);
        h[node * EMB + j] = acc;
    }
}

// out[n][j] = dis[n]*Σ_{s in N(n)} dis[s] h[s][j] + dis[n]^2 h[n][j] + b[j]  (+ReLU)
template <bool RELU>
__global__ void k_agg(const int* __restrict__ row_start, const int* __restrict__ csr_src,
                      const float* __restrict__ dis, const float* __restrict__ h,
                      const float* __restrict__ b, float* __restrict__ out) {
    int t = threadIdx.x;
    int j = t & 31;
    int node = blockIdx.x * 8 + (t >> 5);
    if (node >= N_SERVICES) return;
    int e = row_start[node], e1 = row_start[node + 1];
    float acc0 = 0.f, acc1 = 0.f, acc2 = 0.f, acc3 = 0.f;
    for (; e + 4 <= e1; e += 4) {
        int s0 = csr_src[e], s1 = csr_src[e + 1], s2 = csr_src[e + 2], s3 = csr_src[e + 3];
        acc0 = fmaf(h[s0 * EMB + j], dis[s0], acc0);
        acc1 = fmaf(h[s1 * EMB + j], dis[s1], acc1);
        acc2 = fmaf(h[s2 * EMB + j], dis[s2], acc2);
        acc3 = fmaf(h[s3 * EMB + j], dis[s3], acc3);
    }
    for (; e < e1; ++e) {
        int s0 = csr_src[e];
        acc0 = fmaf(h[s0 * EMB + j], dis[s0], acc0);
    }
    float dn = dis[node];
    float v = dn * ((acc0 + acc1) + (acc2 + acc3)) + dn * dn * h[node * EMB + j] + b[j];
    out[node * EMB + j] = RELU ? fmaxf(v, 0.f) : v;
}

// ---------------- feature gather (emit bf16) ----------------

__global__ void k_gather(const int* __restrict__ user_idx, const int* __restrict__ ctx_idx,
                         const float* __restrict__ user_emb, const float* __restrict__ g2,
                         short* __restrict__ x) {
    int t = blockIdx.x * 256 + threadIdx.x;  // grid exact: BATCH*FIN
    int b = t >> 7, p = t & 127;
    float v;
    if (p < EMB) {
        v = user_emb[user_idx[b] * EMB + p];
    } else {
        int c = (p - EMB) >> 5, j = p & 31;
        v = g2[ctx_idx[b * 3 + c] * EMB + j];
    }
    x[t] = f2bf(v);
}

// ---------------- fc_W transpose+convert: [128][50000] f32 -> [50048][128] bf16 ----

__global__ __launch_bounds__(256) void k_cvtW(const float* __restrict__ W,
                                              short* __restrict__ Wt) {
    __shared__ short lds[128][33];
    int t = threadIdx.x;
    int n0 = blockIdx.x * 32;
    int nx = t & 31;
    int n  = n0 + nx;
    int kg = t >> 5;                 // 0..7
#pragma unroll
    for (int r = 0; r < 16; ++r) {
        int k = r * 8 + kg;
        float v = (n < N_SERVICES) ? W[k * N_SERVICES + n] : 0.f;
        lds[k][nx] = f2bf(v);
    }
    __syncthreads();
    int nr = t >> 3;                 // 0..31
    int kc = (t & 7) * 16;
    short tmp[16];
#pragma unroll
    for (int i = 0; i < 16; ++i) tmp[i] = lds[kc + i][nr];
    short8* dstp = (short8*)(Wt + (size_t)(n0 + nr) * FIN + kc);
    dstp[0] = *(short8*)&tmp[0];
    dstp[1] = *(short8*)&tmp[8];
}

// ---------------- final GEMM via bf16 MFMA, M-loop in kernel ----------------
// Block: 256 thr = 4 waves, 64 cols (wave w -> cols n0+w*16..+16), rows by*1024..+1024.
// B fragments for the block's 64 cols held in registers across the whole M loop.

__global__ __launch_bounds__(256) void k_gemm2(
    const short* __restrict__ A, const short* __restrict__ Bt,
    const float* __restrict__ bias, float* __restrict__ out) {
    int t = threadIdx.x;
    int w = t >> 6;
    int l = t & 63;
    int lr = l & 15;                 // fragment row/col index
    int lg = l >> 4;                 // k-group
    int col = blockIdx.x * 64 + w * 16 + lr;
    int m0 = blockIdx.y * 1024;

    short8 bks[4];
    {
        const short* brow = Bt + (size_t)col * FIN + lg * 8;
#pragma unroll
        for (int ks = 0; ks < 4; ++ks) bks[ks] = *(const short8*)(brow + ks * 32);
    }
    float bv = (col < N_SERVICES) ? bias[col] : 0.f;

    short8 a[4];
    {
        const short* arow = A + (size_t)(m0 + lr) * FIN + lg * 8;
#pragma unroll
        for (int ks = 0; ks < 4; ++ks) a[ks] = *(const short8*)(arow + ks * 32);
    }

    for (int mi = 0; mi < 64; ++mi) {
        int m = m0 + mi * 16;
        short8 an[4];
        if (mi < 63) {
            const short* arow = A + (size_t)(m + 16 + lr) * FIN + lg * 8;
#pragma unroll
            for (int ks = 0; ks < 4; ++ks) an[ks] = *(const short8*)(arow + ks * 32);
        }
        f32x4 acc = {};
#pragma unroll
        for (int ks = 0; ks < 4; ++ks)
            acc = __builtin_amdgcn_mfma_f32_16x16x32_bf16(a[ks], bks[ks], acc, 0, 0, 0);

        if (col < N_SERVICES) {
            int row = m + lg * 4;
#pragma unroll
            for (int r = 0; r < 4; ++r)
                out[(size_t)(row + r) * N_SERVICES + col] = acc[r] + bv;
        }
#pragma unroll
        for (int ks = 0; ks < 4; ++ks) a[ks] = an[ks];
    }
}

// ---------------- launch ----------------

extern "C" void kernel_launch(void* const* d_in, const int* in_sizes, int n_in,
                              void* d_out, int out_size, void* d_ws, size_t ws_size,
                              hipStream_t stream) {
    const int*   user_idx    = (const int*)d_in[0];
    const int*   ctx_idx     = (const int*)d_in[1];
    const int*   ei          = (const int*)d_in[2];
    const float* user_emb    = (const float*)d_in[3];
    const float* service_emb = (const float*)d_in[4];
    const float* W1          = (const float*)d_in[5];
    const float* b1          = (const float*)d_in[6];
    const float* W2          = (const float*)d_in[7];
    const float* b2          = (const float*)d_in[8];
    const float* fcW         = (const float*)d_in[9];
    const float* fcb         = (const float*)d_in[10];
    float* out = (float*)d_out;

    const int* src = ei;
    const int* dst = ei + N_EDGES;

    char* ws = (char*)d_ws;
    float* dis       = (float*)(ws);                   // 200,000
    float* h         = (float*)(ws + 200000);          // 6,400,000
    float* g         = (float*)(ws + 6600000);         // 6,400,000
    short* xb        = (short*)(ws + 13000000);        // 524,288   (degi overlays: dead before k_gather)
    int*   degi      = (int*)  (ws + 13000000);        // 200,000 overlay
    short* Wt        = (short*)(ws + 13524288);        // 12,812,288
    int*   row_start = (int*)  (ws + 26336576);        // 200,004
    int*   cursor    = (int*)  (ws + 26536592);        // 200,000
    int*   csr_src   = (int*)  (ws + 26736592);        // 6,400,000 (tmp overlays head: dead before k_fill)
    int*   tmp       = (int*)  (ws + 26736592);        // 200,000 overlay
    int*   blocksum  = (int*)  (ws + 33136592);        // 1,024    (total ~33.1 MB)

    hipMemsetAsync(degi, 0, N_SERVICES * sizeof(int), stream);

    k_cvtW<<<N_PAD / 32, 256, 0, stream>>>(fcW, Wt);

    // CSR build
    k_count_degi<<<6250, 256, 0, stream>>>(dst, degi);
    k_dis       <<<196,  256, 0, stream>>>(degi, dis);
    k_scan_block<<<196,  256, 0, stream>>>(degi, tmp, blocksum);
    k_scan_part <<<1,    256, 0, stream>>>(blocksum);
    k_scan_fin  <<<196,  256, 0, stream>>>(tmp, blocksum, row_start, cursor);
    k_fill      <<<6250, 256, 0, stream>>>(src, dst, cursor, csr_src);

    // layer 1 (+ReLU)
    k_transform <<<6250, 256, 0, stream>>>(service_emb, W1, h);
    k_agg<true> <<<6250, 256, 0, stream>>>(row_start, csr_src, dis, h, b1, g);
    // layer 2
    k_transform <<<6250, 256, 0, stream>>>(g, W2, h);
    k_agg<false><<<6250, 256, 0, stream>>>(row_start, csr_src, dis, h, b2, g);

    k_gather<<<BATCH * FIN / 256, 256, 0, stream>>>(user_idx, ctx_idx, user_emb, g, xb);

    dim3 grid(N_PAD / 64, 2);
    k_gemm2<<<grid, 256, 0, stream>>>(xb, Wt, fcb, out);
}

// Round 4
// 532.288 us; speedup vs baseline: 2.4526x; 1.0449x over previous
//
#include <hip/hip_runtime.h>

#define N_SERVICES 50000
#define N_PAD      50048   // 782*64
#define N_EDGES    1600000
#define EMB        32
#define BATCH      2048
#define FIN        128     // (CONTEXT+1)*EMB
#define GRID_Y     4
#define MI_PER_BLK (BATCH / GRID_Y / 16)   // 32

typedef __attribute__((ext_vector_type(4))) float f32x4;
typedef __attribute__((ext_vector_type(2))) float f32x2;
typedef __attribute__((ext_vector_type(8))) short short8;

__device__ inline unsigned short f2bf(float f) {
    unsigned u = __float_as_uint(f);
    unsigned r = (u + 0x7FFFu + ((u >> 16) & 1u)) >> 16;
    return (unsigned short)r;
}
__device__ inline float bf2f(unsigned short b) {
    return __uint_as_float(((unsigned)b) << 16);
}

// ---------------- degree count ----------------

__global__ void k_count_degi(const int* __restrict__ dst, int* __restrict__ degi) {
    int e = blockIdx.x * 256 + threadIdx.x;
    if (e < N_EDGES) atomicAdd(&degi[dst[e]], 1);
}

// ---------------- prefix scan (3 kernels), k_dis folded into scan_block ----------

__global__ void k_scan_block(const int* __restrict__ degi, float* __restrict__ dis,
                             int* __restrict__ tmp, int* __restrict__ blocksum) {
    __shared__ int s[256];
    int t = threadIdx.x, i = blockIdx.x * 256 + t;
    int v = (i < N_SERVICES) ? degi[i] : 0;
    if (i < N_SERVICES) dis[i] = rsqrtf((float)(v + 1));  // +1 self-loop
    s[t] = v;
    __syncthreads();
#pragma unroll
    for (int o = 1; o < 256; o <<= 1) {
        int x = 0;
        if (t >= o) x = s[t - o];
        __syncthreads();
        if (t >= o) s[t] += x;
        __syncthreads();
    }
    if (i < N_SERVICES) tmp[i] = s[t] - v;       // exclusive
    if (t == 255) blocksum[blockIdx.x] = s[255];
}

__global__ void k_scan_part(int* __restrict__ blocksum) {
    __shared__ int s[256];
    int t = threadIdx.x;
    int v = (t < 196) ? blocksum[t] : 0;
    s[t] = v;
    __syncthreads();
#pragma unroll
    for (int o = 1; o < 256; o <<= 1) {
        int x = 0;
        if (t >= o) x = s[t - o];
        __syncthreads();
        if (t >= o) s[t] += x;
        __syncthreads();
    }
    if (t < 196) blocksum[t] = s[t] - v;         // exclusive in place
}

__global__ void k_scan_fin(const int* __restrict__ tmp, const int* __restrict__ blocksum,
                           int* __restrict__ row_start, int* __restrict__ cursor) {
    int i = blockIdx.x * 256 + threadIdx.x;
    if (i < N_SERVICES) {
        int v = tmp[i] + blocksum[blockIdx.x];
        row_start[i] = v;
        cursor[i] = v;
    }
    if (i == 0) row_start[N_SERVICES] = N_EDGES;
}

__global__ void k_fill(const int* __restrict__ src, const int* __restrict__ dst,
                       int* __restrict__ cursor, int* __restrict__ csr_src) {
    int e = blockIdx.x * 256 + threadIdx.x;
    if (e < N_EDGES) {
        int pos = atomicAdd(&cursor[dst[e]], 1);
        csr_src[pos] = src[e];
    }
}

// ---------------- GCN pieces ----------------

// h (bf16) = in @ W
__global__ void k_transform(const float* __restrict__ in, const float* __restrict__ W,
                            unsigned short* __restrict__ h) {
    __shared__ float Ws[EMB][EMB + 1];
    __shared__ float rows[8][EMB];
    int t = threadIdx.x;
    int j = t & 31, li = t >> 5;
    for (int i = t; i < EMB * EMB; i += 256) Ws[i >> 5][i & 31] = W[i];
    int node = blockIdx.x * 8 + li;
    if (node < N_SERVICES) rows[li][j] = in[node * EMB + j];
    __syncthreads();
    if (node < N_SERVICES) {
        float acc = 0.f;
#pragma unroll
        for (int k = 0; k < EMB; ++k) acc = fmaf(rows[li][k], Ws[k][j], acc);
        h[node * EMB + j] = f2bf(acc);
    }
}

// out[n][j] = dis[n]*Σ_{s in N(n)} dis[s] h[s][j] + dis[n]^2 h[n][j] + b[j]  (+ReLU)
// 16 lanes per node, each lane owns 2 dims packed in one uint (2×bf16).
template <bool RELU>
__global__ void k_agg(const int* __restrict__ row_start, const int* __restrict__ csr_src,
                      const float* __restrict__ dis, const unsigned int* __restrict__ h2,
                      const float* __restrict__ b, float* __restrict__ out) {
    int t = threadIdx.x;
    int j2 = t & 15;                       // dim pair
    int node = blockIdx.x * 16 + (t >> 4);
    if (node >= N_SERVICES) return;
    int e = row_start[node], e1 = row_start[node + 1];
    float al0 = 0.f, ah0 = 0.f, al1 = 0.f, ah1 = 0.f;
    for (; e + 2 <= e1; e += 2) {
        int s0 = csr_src[e], s1 = csr_src[e + 1];
        float d0 = dis[s0], d1 = dis[s1];
        unsigned v0 = h2[s0 * 16 + j2], v1 = h2[s1 * 16 + j2];
        al0 = fmaf(bf2f((unsigned short)(v0 & 0xffff)), d0, al0);
        ah0 = fmaf(bf2f((unsigned short)(v0 >> 16)), d0, ah0);
        al1 = fmaf(bf2f((unsigned short)(v1 & 0xffff)), d1, al1);
        ah1 = fmaf(bf2f((unsigned short)(v1 >> 16)), d1, ah1);
    }
    if (e < e1) {
        int s0 = csr_src[e];
        float d0 = dis[s0];
        unsigned v0 = h2[s0 * 16 + j2];
        al0 = fmaf(bf2f((unsigned short)(v0 & 0xffff)), d0, al0);
        ah0 = fmaf(bf2f((unsigned short)(v0 >> 16)), d0, ah0);
    }
    float dn = dis[node];
    unsigned vn = h2[node * 16 + j2];
    float lo = dn * (al0 + al1) + dn * dn * bf2f((unsigned short)(vn & 0xffff)) + b[j2 * 2];
    float hi = dn * (ah0 + ah1) + dn * dn * bf2f((unsigned short)(vn >> 16)) + b[j2 * 2 + 1];
    if (RELU) { lo = fmaxf(lo, 0.f); hi = fmaxf(hi, 0.f); }
    f32x2 o; o.x = lo; o.y = hi;
    *(f32x2*)&out[node * EMB + j2 * 2] = o;
}

// ---------------- feature gather (emit bf16) ----------------

__global__ void k_gather(const int* __restrict__ user_idx, const int* __restrict__ ctx_idx,
                         const float* __restrict__ user_emb, const float* __restrict__ g2,
                         unsigned short* __restrict__ x) {
    int t = blockIdx.x * 256 + threadIdx.x;  // grid exact: BATCH*FIN
    int b = t >> 7, p = t & 127;
    float v;
    if (p < EMB) {
        v = user_emb[user_idx[b] * EMB + p];
    } else {
        int c = (p - EMB) >> 5, j = p & 31;
        v = g2[ctx_idx[b * 3 + c] * EMB + j];
    }
    x[t] = f2bf(v);
}

// ---------------- fc_W transpose+convert: [128][50000] f32 -> [50048][128] bf16 ----

__global__ __launch_bounds__(256) void k_cvtW(const float* __restrict__ W,
                                              short* __restrict__ Wt) {
    __shared__ short lds[128][33];
    int t = threadIdx.x;
    int n0 = blockIdx.x * 32;
    int nx = t & 31;
    int n  = n0 + nx;
    int kg = t >> 5;                 // 0..7
#pragma unroll
    for (int r = 0; r < 16; ++r) {
        int k = r * 8 + kg;
        float v = (n < N_SERVICES) ? W[k * N_SERVICES + n] : 0.f;
        lds[k][nx] = (short)f2bf(v);
    }
    __syncthreads();
    int nr = t >> 3;                 // 0..31
    int kc = (t & 7) * 16;
    short tmp[16];
#pragma unroll
    for (int i = 0; i < 16; ++i) tmp[i] = lds[kc + i][nr];
    short8* dstp = (short8*)(Wt + (size_t)(n0 + nr) * FIN + kc);
    dstp[0] = *(short8*)&tmp[0];
    dstp[1] = *(short8*)&tmp[8];
}

// ---------------- final GEMM via bf16 MFMA (swapped operands -> x4 stores) ----
// acc = mfma(Wt_frag, x_frag): C'[n][m] layout => lane holds m = m_tile + (l&15),
// n = nb + (l>>4)*4 + r, r=0..3 consecutive -> one dwordx4 store per tile.

__global__ __launch_bounds__(256) void k_gemm2(
    const short* __restrict__ A, const short* __restrict__ Bt,
    const float* __restrict__ bias, float* __restrict__ out) {
    int t = threadIdx.x;
    int w = t >> 6;
    int l = t & 63;
    int lr = l & 15;
    int lg = l >> 4;
    int nb = blockIdx.x * 64 + w * 16;     // wave's 16-col strip
    int m0 = blockIdx.y * (BATCH / GRID_Y);

    // B fragment (held whole loop): row of Bt = output col nb+lr
    short8 bks[4];
    {
        const short* brow = Bt + (size_t)(nb + lr) * FIN + lg * 8;
#pragma unroll
        for (int ks = 0; ks < 4; ++ks) bks[ks] = *(const short8*)(brow + ks * 32);
    }

    int nst = nb + lg * 4;                 // this lane's 4 output cols
    bool nok = (nst < N_SERVICES);         // N_SERVICES%16==0: group all-in or all-out
    f32x4 bv = {};
    if (nok) bv = *(const f32x4*)&bias[nst];

    const short* arow0 = A + (size_t)(m0 + lr) * FIN + lg * 8;
    float* orow = out + (size_t)(m0 + lr) * N_SERVICES + nst;

    short8 a[4];
#pragma unroll
    for (int ks = 0; ks < 4; ++ks) a[ks] = *(const short8*)(arow0 + ks * 32);

    for (int mi = 0; mi < MI_PER_BLK; ++mi) {
        short8 an[4];
        if (mi < MI_PER_BLK - 1) {
            const short* arow = arow0 + (size_t)(mi + 1) * 16 * FIN;
#pragma unroll
            for (int ks = 0; ks < 4; ++ks) an[ks] = *(const short8*)(arow + ks * 32);
        }
        f32x4 acc = {};
#pragma unroll
        for (int ks = 0; ks < 4; ++ks)
            acc = __builtin_amdgcn_mfma_f32_16x16x32_bf16(bks[ks], a[ks], acc, 0, 0, 0);
        if (nok)
            *(f32x4*)(orow + (size_t)mi * 16 * N_SERVICES) = acc + bv;
#pragma unroll
        for (int ks = 0; ks < 4; ++ks) a[ks] = an[ks];
    }
}

// ---------------- launch ----------------

extern "C" void kernel_launch(void* const* d_in, const int* in_sizes, int n_in,
                              void* d_out, int out_size, void* d_ws, size_t ws_size,
                              hipStream_t stream) {
    const int*   user_idx    = (const int*)d_in[0];
    const int*   ctx_idx     = (const int*)d_in[1];
    const int*   ei          = (const int*)d_in[2];
    const float* user_emb    = (const float*)d_in[3];
    const float* service_emb = (const float*)d_in[4];
    const float* W1          = (const float*)d_in[5];
    const float* b1          = (const float*)d_in[6];
    const float* W2          = (const float*)d_in[7];
    const float* b2          = (const float*)d_in[8];
    const float* fcW         = (const float*)d_in[9];
    const float* fcb         = (const float*)d_in[10];
    float* out = (float*)d_out;

    const int* src = ei;
    const int* dst = ei + N_EDGES;

    char* ws = (char*)d_ws;
    float*          dis       = (float*)(ws);                   // 200,000
    unsigned short* h         = (unsigned short*)(ws + 200000); // 3,200,000 (bf16)
    float*          g         = (float*)(ws + 3400000);         // 6,400,000
    unsigned short* xb        = (unsigned short*)(ws + 9800000);//   524,288
    int*            degi      = (int*)(ws + 9800000);           // 200,000 overlay (dead before k_gather)
    short*          Wt        = (short*)(ws + 10324288);        // 12,812,288
    int*            row_start = (int*)(ws + 23136576);          // 200,004
    int*            cursor    = (int*)(ws + 23336580);          // 200,000
    int*            csr_src   = (int*)(ws + 23536580);          // 6,400,000
    int*            tmp       = (int*)(ws + 23536580);          // 200,000 overlay (dead before k_fill)
    int*            blocksum  = (int*)(ws + 29936580);          // 1,024   (total ~29.9 MB)

    hipMemsetAsync(degi, 0, N_SERVICES * sizeof(int), stream);

    k_cvtW<<<N_PAD / 32, 256, 0, stream>>>(fcW, Wt);

    // CSR build (+dis folded into scan_block)
    k_count_degi<<<6250, 256, 0, stream>>>(dst, degi);
    k_scan_block<<<196,  256, 0, stream>>>(degi, dis, tmp, blocksum);
    k_scan_part <<<1,    256, 0, stream>>>(blocksum);
    k_scan_fin  <<<196,  256, 0, stream>>>(tmp, blocksum, row_start, cursor);
    k_fill      <<<6250, 256, 0, stream>>>(src, dst, cursor, csr_src);

    // layer 1 (+ReLU)
    k_transform <<<6250, 256, 0, stream>>>(service_emb, W1, h);
    k_agg<true> <<<3125, 256, 0, stream>>>(row_start, csr_src, dis, (const unsigned int*)h, b1, g);
    // layer 2
    k_transform <<<6250, 256, 0, stream>>>(g, W2, h);
    k_agg<false><<<3125, 256, 0, stream>>>(row_start, csr_src, dis, (const unsigned int*)h, b2, g);

    k_gather<<<BATCH * FIN / 256, 256, 0, stream>>>(user_idx, ctx_idx, user_emb, g, xb);

    dim3 grid(N_PAD / 64, GRID_Y);
    k_gemm2<<<grid, 256, 0, stream>>>((const short*)xb, Wt, fcb, out);
}

// Round 5
// 417.694 us; speedup vs baseline: 3.1254x; 1.2743x over previous
//
#include <hip/hip_runtime.h>

#define N_SERVICES 50000
#define N_PAD      50048   // 782*64
#define N_EDGES    1600000
#define N_CTX      6144    // BATCH*CONTEXT
#define EMB        32
#define BATCH      2048
#define FIN        128     // (CONTEXT+1)*EMB
#define GEMM_BLKS  1024
#define N_TILES    782
#define M_CHUNKS   32      // 2048 rows / 64

typedef __attribute__((ext_vector_type(4))) float f32x4;
typedef __attribute__((ext_vector_type(2))) float f32x2;
typedef __attribute__((ext_vector_type(8))) short short8;

__device__ inline unsigned short f2bf(float f) {
    unsigned u = __float_as_uint(f);
    unsigned r = (u + 0x7FFFu + ((u >> 16) & 1u)) >> 16;
    return (unsigned short)r;
}
__device__ inline float bf2f(unsigned short b) {
    return __uint_as_float(((unsigned)b) << 16);
}

// ---------------- degree count ----------------

__global__ void k_count_degi(const int* __restrict__ dst, int* __restrict__ degi) {
    int e = blockIdx.x * 256 + threadIdx.x;
    if (e < N_EDGES) atomicAdd(&degi[dst[e]], 1);
}

// ---------------- prefix scan (3 kernels); dis folded in ----------------

__global__ void k_scan_block(const int* __restrict__ degi, float* __restrict__ dis,
                             int* __restrict__ tmp, int* __restrict__ blocksum) {
    __shared__ int s[256];
    int t = threadIdx.x, i = blockIdx.x * 256 + t;
    int v = (i < N_SERVICES) ? degi[i] : 0;
    if (i < N_SERVICES) dis[i] = rsqrtf((float)(v + 1));  // +1 self-loop
    s[t] = v;
    __syncthreads();
#pragma unroll
    for (int o = 1; o < 256; o <<= 1) {
        int x = 0;
        if (t >= o) x = s[t - o];
        __syncthreads();
        if (t >= o) s[t] += x;
        __syncthreads();
    }
    if (i < N_SERVICES) tmp[i] = s[t] - v;       // exclusive
    if (t == 255) blocksum[blockIdx.x] = s[255];
}

__global__ void k_scan_part(int* __restrict__ blocksum) {
    __shared__ int s[256];
    int t = threadIdx.x;
    int v = (t < 196) ? blocksum[t] : 0;
    s[t] = v;
    __syncthreads();
#pragma unroll
    for (int o = 1; o < 256; o <<= 1) {
        int x = 0;
        if (t >= o) x = s[t - o];
        __syncthreads();
        if (t >= o) s[t] += x;
        __syncthreads();
    }
    if (t < 196) blocksum[t] = s[t] - v;         // exclusive in place
}

// also marks the context-node mask (mask zeroed earlier in k_cvtW)
__global__ void k_scan_fin(const int* __restrict__ tmp, const int* __restrict__ blocksum,
                           int* __restrict__ row_start, int* __restrict__ cursor,
                           const int* __restrict__ ctx_idx, int* __restrict__ mask) {
    int i = blockIdx.x * 256 + threadIdx.x;
    if (i < N_SERVICES) {
        int v = tmp[i] + blocksum[blockIdx.x];
        row_start[i] = v;
        cursor[i] = v;
    }
    if (i < N_CTX) mask[ctx_idx[i]] = 1;
    if (i == 0) row_start[N_SERVICES] = N_EDGES;
}

__global__ void k_fill(const int* __restrict__ src, const int* __restrict__ dst,
                       int* __restrict__ cursor, int* __restrict__ csr_src) {
    int e = blockIdx.x * 256 + threadIdx.x;
    if (e < N_EDGES) {
        int pos = atomicAdd(&cursor[dst[e]], 1);
        csr_src[pos] = src[e];
    }
}

// ---------------- GCN pieces ----------------

// h (bf16) = in @ W
__global__ void k_transform(const float* __restrict__ in, const float* __restrict__ W,
                            unsigned short* __restrict__ h) {
    __shared__ float Ws[EMB][EMB + 1];
    __shared__ float rows[8][EMB];
    int t = threadIdx.x;
    int j = t & 31, li = t >> 5;
    for (int i = t; i < EMB * EMB; i += 256) Ws[i >> 5][i & 31] = W[i];
    int node = blockIdx.x * 8 + li;
    if (node < N_SERVICES) rows[li][j] = in[node * EMB + j];
    __syncthreads();
    if (node < N_SERVICES) {
        float acc = 0.f;
#pragma unroll
        for (int k = 0; k < EMB; ++k) acc = fmaf(rows[li][k], Ws[k][j], acc);
        h[node * EMB + j] = f2bf(acc);
    }
}

// out[n][j] = dis[n]*Σ_{s in N(n)} dis[s] h[s][j] + dis[n]^2 h[n][j] + b[j]  (+ReLU)
// 16 lanes per node, each lane owns 2 dims packed in one uint (2×bf16).
template <bool RELU, bool MASKED>
__global__ void k_agg(const int* __restrict__ row_start, const int* __restrict__ csr_src,
                      const float* __restrict__ dis, const unsigned int* __restrict__ h2,
                      const float* __restrict__ b, const int* __restrict__ mask,
                      float* __restrict__ out) {
    int t = threadIdx.x;
    int j2 = t & 15;                       // dim pair
    int node = blockIdx.x * 16 + (t >> 4);
    if (node >= N_SERVICES) return;
    if (MASKED && !mask[node]) return;
    int e = row_start[node], e1 = row_start[node + 1];
    float al0 = 0.f, ah0 = 0.f, al1 = 0.f, ah1 = 0.f;
    for (; e + 2 <= e1; e += 2) {
        int s0 = csr_src[e], s1 = csr_src[e + 1];
        float d0 = dis[s0], d1 = dis[s1];
        unsigned v0 = h2[s0 * 16 + j2], v1 = h2[s1 * 16 + j2];
        al0 = fmaf(bf2f((unsigned short)(v0 & 0xffff)), d0, al0);
        ah0 = fmaf(bf2f((unsigned short)(v0 >> 16)), d0, ah0);
        al1 = fmaf(bf2f((unsigned short)(v1 & 0xffff)), d1, al1);
        ah1 = fmaf(bf2f((unsigned short)(v1 >> 16)), d1, ah1);
    }
    if (e < e1) {
        int s0 = csr_src[e];
        float d0 = dis[s0];
        unsigned v0 = h2[s0 * 16 + j2];
        al0 = fmaf(bf2f((unsigned short)(v0 & 0xffff)), d0, al0);
        ah0 = fmaf(bf2f((unsigned short)(v0 >> 16)), d0, ah0);
    }
    float dn = dis[node];
    unsigned vn = h2[node * 16 + j2];
    float lo = dn * (al0 + al1) + dn * dn * bf2f((unsigned short)(vn & 0xffff)) + b[j2 * 2];
    float hi = dn * (ah0 + ah1) + dn * dn * bf2f((unsigned short)(vn >> 16)) + b[j2 * 2 + 1];
    if (RELU) { lo = fmaxf(lo, 0.f); hi = fmaxf(hi, 0.f); }
    f32x2 o; o.x = lo; o.y = hi;
    *(f32x2*)&out[node * EMB + j2 * 2] = o;
}

// ---------------- feature gather (emit bf16) ----------------

__global__ void k_gather(const int* __restrict__ user_idx, const int* __restrict__ ctx_idx,
                         const float* __restrict__ user_emb, const float* __restrict__ g2,
                         unsigned short* __restrict__ x) {
    int t = blockIdx.x * 256 + threadIdx.x;  // grid exact: BATCH*FIN
    int b = t >> 7, p = t & 127;
    float v;
    if (p < EMB) {
        v = user_emb[user_idx[b] * EMB + p];
    } else {
        int c = (p - EMB) >> 5, j = p & 31;
        v = g2[ctx_idx[b * 3 + c] * EMB + j];
    }
    x[t] = f2bf(v);
}

// ---------------- fc_W transpose+convert + zero degi/mask ----------------

__global__ __launch_bounds__(256) void k_cvtW(const float* __restrict__ W,
                                              short* __restrict__ Wt,
                                              int* __restrict__ degi,
                                              int* __restrict__ mask) {
    int gid = blockIdx.x * 256 + threadIdx.x;
    if (gid < N_SERVICES) { degi[gid] = 0; mask[gid] = 0; }

    __shared__ short lds[128][33];
    int t = threadIdx.x;
    int n0 = blockIdx.x * 32;
    int nx = t & 31;
    int n  = n0 + nx;
    int kg = t >> 5;                 // 0..7
#pragma unroll
    for (int r = 0; r < 16; ++r) {
        int k = r * 8 + kg;
        float v = (n < N_SERVICES) ? W[k * N_SERVICES + n] : 0.f;
        lds[k][nx] = (short)f2bf(v);
    }
    __syncthreads();
    int nr = t >> 3;                 // 0..31
    int kc = (t & 7) * 16;
    short tmp[16];
#pragma unroll
    for (int i = 0; i < 16; ++i) tmp[i] = lds[kc + i][nr];
    short8* dstp = (short8*)(Wt + (size_t)(n0 + nr) * FIN + kc);
    dstp[0] = *(short8*)&tmp[0];
    dstp[1] = *(short8*)&tmp[8];
}

// ---------------- final GEMM: persistent blocks, A in registers ----------------
// 1024 blocks (4/CU, all resident). Block owns m-chunk mc = bid&31 (64 rows,
// A frags a[4][4] in regs for the whole kernel) and grid-strides over n-tiles.
// Swapped mfma(B,A): lane stores 4 consecutive output cols -> one dwordx4 (nt).

__global__ __launch_bounds__(256, 4) void k_gemm3(
    const short* __restrict__ A, const short* __restrict__ Bt,
    const float* __restrict__ bias, float* __restrict__ out) {
    int t = threadIdx.x;
    int w = t >> 6;
    int l = t & 63;
    int lr = l & 15;
    int lg = l >> 4;
    int mc = blockIdx.x & (M_CHUNKS - 1);
    int m_base = mc * 64;

    short8 a[4][4];
#pragma unroll
    for (int mi = 0; mi < 4; ++mi) {
        const short* arow = A + (size_t)(m_base + mi * 16 + lr) * FIN + lg * 8;
#pragma unroll
        for (int ks = 0; ks < 4; ++ks) a[mi][ks] = *(const short8*)(arow + ks * 32);
    }

    for (int job = blockIdx.x; job < N_TILES * M_CHUNKS; job += GEMM_BLKS) {
        int nt = job >> 5;               // mc = job & 31 is constant per block
        int nb = nt * 64 + w * 16;
        const short* brow = Bt + (size_t)(nb + lr) * FIN + lg * 8;
        short8 b0 = *(const short8*)(brow);
        short8 b1 = *(const short8*)(brow + 32);
        short8 b2 = *(const short8*)(brow + 64);
        short8 b3 = *(const short8*)(brow + 96);
        int nst = nb + lg * 4;           // lane's 4 output cols (50000%4==0: all-in/out)
        bool nok = (nst < N_SERVICES);
        f32x4 bv = {};
        if (nok) bv = *(const f32x4*)&bias[nst];
#pragma unroll
        for (int mi = 0; mi < 4; ++mi) {
            f32x4 acc = {};
            acc = __builtin_amdgcn_mfma_f32_16x16x32_bf16(b0, a[mi][0], acc, 0, 0, 0);
            acc = __builtin_amdgcn_mfma_f32_16x16x32_bf16(b1, a[mi][1], acc, 0, 0, 0);
            acc = __builtin_amdgcn_mfma_f32_16x16x32_bf16(b2, a[mi][2], acc, 0, 0, 0);
            acc = __builtin_amdgcn_mfma_f32_16x16x32_bf16(b3, a[mi][3], acc, 0, 0, 0);
            if (nok) {
                f32x4 v = acc + bv;
                __builtin_nontemporal_store(
                    v, (f32x4*)(out + (size_t)(m_base + mi * 16 + lr) * N_SERVICES + nst));
            }
        }
    }
}

// ---------------- launch ----------------

extern "C" void kernel_launch(void* const* d_in, const int* in_sizes, int n_in,
                              void* d_out, int out_size, void* d_ws, size_t ws_size,
                              hipStream_t stream) {
    const int*   user_idx    = (const int*)d_in[0];
    const int*   ctx_idx     = (const int*)d_in[1];
    const int*   ei          = (const int*)d_in[2];
    const float* user_emb    = (const float*)d_in[3];
    const float* service_emb = (const float*)d_in[4];
    const float* W1          = (const float*)d_in[5];
    const float* b1          = (const float*)d_in[6];
    const float* W2          = (const float*)d_in[7];
    const float* b2          = (const float*)d_in[8];
    const float* fcW         = (const float*)d_in[9];
    const float* fcb         = (const float*)d_in[10];
    float* out = (float*)d_out;

    const int* src = ei;
    const int* dst = ei + N_EDGES;

    char* ws = (char*)d_ws;
    float*          dis       = (float*)(ws);                   // 200,000
    unsigned short* h         = (unsigned short*)(ws + 200000); // 3,200,000 (bf16)
    float*          g         = (float*)(ws + 3400000);         // 6,400,000
    unsigned short* xb        = (unsigned short*)(ws + 9800000);//   524,288
    int*            degi      = (int*)(ws + 9800000);           // 200,000 overlay (dead before k_gather)
    short*          Wt        = (short*)(ws + 10324288);        // 12,812,288
    int*            row_start = (int*)(ws + 23136576);          // 200,004
    int*            cursor    = (int*)(ws + 23336580);          // 200,000
    int*            csr_src   = (int*)(ws + 23536580);          // 6,400,000
    int*            tmp       = (int*)(ws + 23536580);          // 200,000 overlay (dead before k_fill)
    int*            blocksum  = (int*)(ws + 29936580);          // 1,024
    int*            mask      = (int*)(ws + 29937604);          // 200,000 (total ~30.1 MB)

    // cvtW also zeroes degi + mask (runs first)
    k_cvtW<<<N_PAD / 32, 256, 0, stream>>>(fcW, Wt, degi, mask);

    // CSR build (+dis in scan_block, +ctx-mask marking in scan_fin)
    k_count_degi<<<6250, 256, 0, stream>>>(dst, degi);
    k_scan_block<<<196,  256, 0, stream>>>(degi, dis, tmp, blocksum);
    k_scan_part <<<1,    256, 0, stream>>>(blocksum);
    k_scan_fin  <<<196,  256, 0, stream>>>(tmp, blocksum, row_start, cursor, ctx_idx, mask);
    k_fill      <<<6250, 256, 0, stream>>>(src, dst, cursor, csr_src);

    // layer 1 (+ReLU), all nodes
    k_transform        <<<6250, 256, 0, stream>>>(service_emb, W1, h);
    k_agg<true, false> <<<3125, 256, 0, stream>>>(row_start, csr_src, dis,
                                                  (const unsigned int*)h, b1, mask, g);
    // layer 2, only context nodes
    k_transform        <<<6250, 256, 0, stream>>>(g, W2, h);
    k_agg<false, true> <<<3125, 256, 0, stream>>>(row_start, csr_src, dis,
                                                  (const unsigned int*)h, b2, mask, g);

    k_gather<<<BATCH * FIN / 256, 256, 0, stream>>>(user_idx, ctx_idx, user_emb, g, xb);

    k_gemm3<<<GEMM_BLKS, 256, 0, stream>>>((const short*)xb, Wt, fcb, out);
}